// Round 3
// baseline (45.853 us; speedup 1.0000x reference)
//
#include <hip/hip_runtime.h>

// out(x) = sum_{k=0..30} sigmoid(100*(x - (-15.5 + k))) - 16
// Offsets 1.0 apart, sharpness 100 => only the NEAREST offset's sigmoid is
// non-saturated (others within 2e-22 of 0/1). Closed form (exact to fp32):
//   t = x + 15.5; j = clamp(rint(t), 0, 30); d = t - j
//   out = j + 1/(1 + exp(-100*d)) - 16
//
// R1 counters: FETCH=67MB (L3 half-absorbed the 134MB input), WRITE=134MB.
// Input+output footprint 268MB > 256MiB L3 -> write stream evicts the input.
// Output is write-once -> non-temporal stores keep it out of L2/L3 so the
// input stays L3-resident across graph replays.
//
// NOTE: __builtin_nontemporal_store requires a native clang vector type, not
// HIP's float4 class -> use ext_vector_type(4).

typedef float floatx4 __attribute__((ext_vector_type(4)));

__device__ __forceinline__ float staircase(float x) {
    float t = x + 15.5f;
    float j = rintf(t);                       // v_rndne_f32
    j = fminf(fmaxf(j, 0.0f), 30.0f);         // clamp to valid offset range
    float d = t - j;
    // exp(-100*d) = exp2(-100*log2(e)*d); extremes saturate correctly:
    // exp2(+big)=inf -> rcp=0 ; exp2(-big)=0 -> rcp(1)=1.
    float e = __builtin_amdgcn_exp2f(d * -144.26950408889634f);
    float s = __builtin_amdgcn_rcpf(1.0f + e);
    return j + s - 16.0f;
}

__global__ __launch_bounds__(256) void Roundings_24154896073503_kernel(
        const float* __restrict__ x, float* __restrict__ out, int n4) {
    const floatx4* __restrict__ x4 = reinterpret_cast<const floatx4*>(x);
    floatx4* __restrict__ o4 = reinterpret_cast<floatx4*>(out);
    int idx = blockIdx.x * blockDim.x + threadIdx.x;
    int stride = gridDim.x * blockDim.x;
    for (int i = idx; i < n4; i += stride) {
        floatx4 v = x4[i];                    // cached load: keep input in L3
        floatx4 r;
        r.x = staircase(v.x);
        r.y = staircase(v.y);
        r.z = staircase(v.z);
        r.w = staircase(v.w);
        __builtin_nontemporal_store(r, &o4[i]);  // global_store_dwordx4 ... nt
    }
}

__global__ void Roundings_tail_kernel(const float* __restrict__ x,
                                      float* __restrict__ out, int start, int n) {
    int i = start + blockIdx.x * blockDim.x + threadIdx.x;
    if (i < n) out[i] = staircase(x[i]);
}

extern "C" void kernel_launch(void* const* d_in, const int* in_sizes, int n_in,
                              void* d_out, int out_size, void* d_ws, size_t ws_size,
                              hipStream_t stream) {
    const float* x = (const float*)d_in[0];
    float* out = (float*)d_out;
    int n = in_sizes[0];
    int n4 = n / 4;

    const int block = 256;
    int grid = (n4 + block - 1) / block;
    if (grid > 2048) grid = 2048;
    if (grid > 0) {
        Roundings_24154896073503_kernel<<<grid, block, 0, stream>>>(x, out, n4);
    }

    int done = n4 * 4;
    int rem = n - done;
    if (rem > 0) {
        int tgrid = (rem + block - 1) / block;
        Roundings_tail_kernel<<<tgrid, block, 0, stream>>>(x, out, done, n);
    }
}

// Round 4
// 45.377 us; speedup vs baseline: 1.0105x; 1.0105x over previous
//
#include <hip/hip_runtime.h>

// out(x) = sum_{k=0..30} sigmoid(100*(x - (-15.5 + k))) - 16
// Offsets 1.0 apart, sharpness 100 => only the NEAREST offset's sigmoid is
// non-saturated (others within 2e-22 of 0/1). Closed form (exact to fp32):
//   t = x + 15.5; j = clamp(rint(t), 0, 30); d = t - j
//   out = j + 1/(1 + exp(-100*d)) - 16
//
// Traffic-identical to a 268MB fp32 copy -> floor = 42.6us at the measured
// 6.29 TB/s copy ceiling. R3 falsified the nt-store theory: Infinity Cache is
// memory-side, writes allocate regardless of nt -> input stays half-resident
// (FETCH=67MB). This round: plain stores (nt was ~neutral-negative) + 2x
// unrolled grid-stride with both loads issued up front (double the MLP).

typedef float floatx4 __attribute__((ext_vector_type(4)));

__device__ __forceinline__ float staircase(float x) {
    float t = x + 15.5f;
    float j = rintf(t);                       // v_rndne_f32
    j = fminf(fmaxf(j, 0.0f), 30.0f);         // clamp to valid offset range
    float d = t - j;
    // exp(-100*d) = exp2(-100*log2(e)*d); extremes saturate correctly:
    // exp2(+big)=inf -> rcp=0 ; exp2(-big)=0 -> rcp(1)=1.
    float e = __builtin_amdgcn_exp2f(d * -144.26950408889634f);
    float s = __builtin_amdgcn_rcpf(1.0f + e);
    return j + s - 16.0f;
}

__device__ __forceinline__ floatx4 staircase4(floatx4 v) {
    floatx4 r;
    r.x = staircase(v.x);
    r.y = staircase(v.y);
    r.z = staircase(v.z);
    r.w = staircase(v.w);
    return r;
}

__global__ __launch_bounds__(256) void Roundings_24154896073503_kernel(
        const float* __restrict__ x, float* __restrict__ out, int n4) {
    const floatx4* __restrict__ x4 = reinterpret_cast<const floatx4*>(x);
    floatx4* __restrict__ o4 = reinterpret_cast<floatx4*>(out);
    int idx = blockIdx.x * blockDim.x + threadIdx.x;
    int stride = gridDim.x * blockDim.x;

    int i = idx;
    // 2x unrolled main loop: issue both loads before any compute/store so two
    // global_load_dwordx4 are in flight per wave iteration (MLP=2).
    for (; i + stride < n4; i += 2 * stride) {
        floatx4 v0 = x4[i];
        floatx4 v1 = x4[i + stride];
        o4[i]          = staircase4(v0);
        o4[i + stride] = staircase4(v1);
    }
    if (i < n4) {
        o4[i] = staircase4(x4[i]);
    }
}

__global__ void Roundings_tail_kernel(const float* __restrict__ x,
                                      float* __restrict__ out, int start, int n) {
    int i = start + blockIdx.x * blockDim.x + threadIdx.x;
    if (i < n) out[i] = staircase(x[i]);
}

extern "C" void kernel_launch(void* const* d_in, const int* in_sizes, int n_in,
                              void* d_out, int out_size, void* d_ws, size_t ws_size,
                              hipStream_t stream) {
    const float* x = (const float*)d_in[0];
    float* out = (float*)d_out;
    int n = in_sizes[0];
    int n4 = n / 4;

    const int block = 256;
    int grid = (n4 + block - 1) / block;
    if (grid > 2048) grid = 2048;
    if (grid > 0) {
        Roundings_24154896073503_kernel<<<grid, block, 0, stream>>>(x, out, n4);
    }

    int done = n4 * 4;
    int rem = n - done;
    if (rem > 0) {
        int tgrid = (rem + block - 1) / block;
        Roundings_tail_kernel<<<tgrid, block, 0, stream>>>(x, out, done, n);
    }
}